// Round 5
// baseline (112.440 us; speedup 1.0000x reference)
//
#include <hip/hip_runtime.h>

#define NB 512
#define NT 256
#define NC 384
#define NH 64

typedef __bf16 bf16x8 __attribute__((ext_vector_type(8)));
typedef float f32x16 __attribute__((ext_vector_type(16)));
typedef unsigned int u32;
typedef unsigned int u32x4 __attribute__((ext_vector_type(4)));
typedef unsigned short u16;

__device__ __forceinline__ u16 f2bf(float x) {
  u32 u = __builtin_bit_cast(u32, x);
  u32 r = (u + 0x7fffu + ((u >> 16) & 1u)) >> 16;  // RNE
  return (u16)r;
}
__device__ __forceinline__ u32 pkbf(float lo, float hi) {
  u32 r;
  asm("v_cvt_pk_bf16_f32 %0, %1, %2" : "=v"(r) : "v"(lo), "v"(hi));
  return r;
}
__device__ __forceinline__ void pl32swap(u32& a, u32& b) {
  asm volatile("v_permlane32_swap_b32 %0, %1" : "+v"(a), "+v"(b));
}

// ---------------- kernel 0: W (3x[64][384] f32) -> combined [192][384] bf16 ----
__global__ __launch_bounds__(256) void wconv_k(const float* __restrict__ wk,
                                               const float* __restrict__ wq,
                                               const float* __restrict__ wv,
                                               u16* __restrict__ wb) {
  int i = blockIdx.x * 256 + threadIdx.x;
  if (i >= 192 * NC) return;
  int row = i / NC, col = i - row * NC;
  const float* s = (row < 64) ? wk : ((row < 128) ? wq : wv);
  wb[i] = f2bf(s[(row & 63) * NC + col]);
}

// ---------------- kernel 1: QKV projection GEMM (barrier-free, 32x32 MFMA) ---
// C[m][n] = sum_c x[m][c] * W[n][c];  M=131072, K=384, N=192
// 1024 threads = 16 waves = 8 row-groups x 2 col-groups; wave = 32 rows x 96 cols.
// W resident in LDS (147 KB, XOR-swizzled 16B granules); x streamed
// global->regs->A-frags (depth-3 prefetch, 4 float4/step); 6 ds_read_b128 +
// 6 mfma_32x32x16 per step; zero barriers in the K-loop.
__global__ __launch_bounds__(1024) void qkv_gemm(const float* __restrict__ x,
                                                 const u16* __restrict__ wb,
                                                 u16* __restrict__ kws,
                                                 u16* __restrict__ qws,
                                                 u16* __restrict__ vws) {
  __shared__ u16 Wl[192 * 384];  // 147456 B; row stride 768 B; pos p holds granule p^(row&7)
  const int tid = threadIdx.x;
  const int lane = tid & 63, w = tid >> 6;
  const int l31 = lane & 31, gl = lane >> 5;
  const int rg = w >> 1, cg = w & 1;
  const size_t m0 = (size_t)blockIdx.x * 256;

  const float* xpf = x + (m0 + (size_t)(rg * 32 + l31)) * NC + gl * 8;

  // --- prefetch x for steps 0..2 (4 float4 each: k-halves {0..7} and {16..23} rel) ---
  float4 p0[3], p1[3], p2[3], p3[3];
#pragma unroll
  for (int s = 0; s < 3; ++s) {
    p0[s] = *(const float4*)(xpf + s * 32);
    p1[s] = *(const float4*)(xpf + s * 32 + 4);
    p2[s] = *(const float4*)(xpf + s * 32 + 16);
    p3[s] = *(const float4*)(xpf + s * 32 + 20);
  }

  // --- stage W into LDS, swizzled: Wl[row][gs] = wb[row][gs ^ (row&7)] ---
#pragma unroll
  for (int i = 0; i < 9; ++i) {
    int idx = tid + i * 1024;          // 0..9215
    int row = idx / 48, gs = idx - row * 48;
    int gk = gs ^ (row & 7);
    uint4 d = *(const uint4*)(wb + row * NC + gk * 8);
    *(uint4*)((char*)Wl + row * 768 + gs * 16) = d;
  }
  __syncthreads();

  f32x16 acc[3];
#pragma unroll
  for (int nt = 0; nt < 3; ++nt) {
    f32x16 z = {};
    acc[nt] = z;
  }

  // --- K-loop: 12 steps of K=32, fully independent per wave ---
#pragma unroll
  for (int kk = 0; kk < 12; ++kk) {
    const int st = kk % 3;
    u32 a00 = pkbf(p0[st].x, p0[st].y);
    u32 a01 = pkbf(p0[st].z, p0[st].w);
    u32 a02 = pkbf(p1[st].x, p1[st].y);
    u32 a03 = pkbf(p1[st].z, p1[st].w);
    u32x4 av0 = {a00, a01, a02, a03};
    bf16x8 af0 = __builtin_bit_cast(bf16x8, av0);
    u32 a10 = pkbf(p2[st].x, p2[st].y);
    u32 a11 = pkbf(p2[st].z, p2[st].w);
    u32 a12 = pkbf(p3[st].x, p3[st].y);
    u32 a13 = pkbf(p3[st].z, p3[st].w);
    u32x4 av1 = {a10, a11, a12, a13};
    bf16x8 af1 = __builtin_bit_cast(bf16x8, av1);
    if (kk < 9) {  // refill slot st with step kk+3
      p0[st] = *(const float4*)(xpf + (kk + 3) * 32);
      p1[st] = *(const float4*)(xpf + (kk + 3) * 32 + 4);
      p2[st] = *(const float4*)(xpf + (kk + 3) * 32 + 16);
      p3[st] = *(const float4*)(xpf + (kk + 3) * 32 + 20);
    }
#pragma unroll
    for (int nt = 0; nt < 3; ++nt) {
      int brow = cg * 96 + nt * 32 + l31;
      bf16x8 b = *(const bf16x8*)((const char*)Wl + brow * 768 +
                                  (((kk * 4 + gl) ^ (brow & 7)) << 4));
      acc[nt] = __builtin_amdgcn_mfma_f32_32x32x16_bf16(af0, b, acc[nt], 0, 0, 0);
    }
#pragma unroll
    for (int nt = 0; nt < 3; ++nt) {
      int brow = cg * 96 + nt * 32 + l31;
      bf16x8 b = *(const bf16x8*)((const char*)Wl + brow * 768 +
                                  (((kk * 4 + 2 + gl) ^ (brow & 7)) << 4));
      acc[nt] = __builtin_amdgcn_mfma_f32_32x32x16_bf16(af1, b, acc[nt], 0, 0, 0);
    }
  }

  // --- epilogue: acc -> LDS (row-major [256][192] bf16) -> full-line stores ---
  __syncthreads();  // all waves done reading W
#pragma unroll
  for (int nt = 0; nt < 3; ++nt) {
    int col = cg * 96 + nt * 32 + l31;
#pragma unroll
    for (int r = 0; r < 16; ++r) {
      int mloc = rg * 32 + (r & 3) + 8 * (r >> 2) + 4 * gl;
      *((u16*)((char*)Wl + mloc * 384) + col) = f2bf(acc[nt][r]);
    }
  }
  __syncthreads();
  {
    u16* const bases[3] = {kws, qws, vws};
#pragma unroll
    for (int t = 0; t < 3; ++t) {
#pragma unroll
      for (int j = 0; j < 2; ++j) {
        int idx = tid + j * 1024;      // 0..2047
        int row = idx >> 3, c16 = idx & 7;
        uint4 d = *(const uint4*)((const char*)Wl + row * 384 + t * 128 + c16 * 16);
        *(uint4*)(bases[t] + (m0 + row) * NH + c16 * 8) = d;
      }
    }
  }
}

// ---------------- kernel 2: fused causal attention per batch -----------------
// swapped layout: S^T[s][t] = sum_h K[s][h] Q[t][h]; lane owns full row (t = lane&31)
// P^T -> PV B-frags built fully in-register via cvt_pk + permlane32_swap (T12)
__global__ __launch_bounds__(256) void attn_k(const u16* __restrict__ kws,
                                              const u16* __restrict__ qws,
                                              const u16* __restrict__ vws,
                                              float* __restrict__ out) {
  __shared__ u16 Klds[256 * 64];      // 32 KB, [s][h], swizzled
  __shared__ u16 VT[64 * 256];        // 32 KB, [h][s], swizzled
  const int b = blockIdx.x;
  const int tid = threadIdx.x, lane = tid & 63, w = tid >> 6;
  const int gl = lane >> 5, l31 = lane & 31;
  const u16* kb = kws + (size_t)b * NT * NH;
  const u16* qb = qws + (size_t)b * NT * NH;
  const u16* vb = vws + (size_t)b * NT * NH;

#pragma unroll
  for (int p = 0; p < 8; ++p) {
    int u = tid + p * 256;
    int row = u >> 3, c16 = u & 7;
    uint4 d = *(const uint4*)(kb + row * 64 + c16 * 8);
    *(uint4*)((char*)Klds + row * 128 + ((c16 * 16) ^ ((row & 7) << 4))) = d;
  }
#pragma unroll
  for (int p = 0; p < 8; ++p) {
    int u = tid + p * 256;
    int s = u >> 3, h0 = (u & 7) * 8;
    uint4 d = *(const uint4*)(vb + s * 64 + h0);
    u32 ww[4] = {d.x, d.y, d.z, d.w};
#pragma unroll
    for (int j = 0; j < 4; ++j) {
      int h = h0 + 2 * j;
      *(u16*)((char*)VT + h * 512 + ((s * 2) ^ ((h & 7) << 4))) = (u16)(ww[j] & 0xffffu);
      *(u16*)((char*)VT + (h + 1) * 512 + ((s * 2) ^ (((h + 1) & 7) << 4))) = (u16)(ww[j] >> 16);
    }
  }
  __syncthreads();

  const float cexp = 0.05103103630798287f * 1.4426950408889634f;  // C^-0.5 * log2(e)

#pragma unroll
  for (int pass = 0; pass < 2; ++pass) {
    const int qt = (pass == 0) ? w : 7 - w;
    const int t0 = qt * 32;

    bf16x8 bq[4];
#pragma unroll
    for (int kk = 0; kk < 4; ++kk)
      bq[kk] = *(const bf16x8*)(qb + (t0 + l31) * NH + kk * 16 + gl * 8);

    f32x16 sf[8];
#pragma unroll
    for (int f = 0; f < 8; ++f) {
      if (f <= qt) {
        f32x16 z = {};
        sf[f] = z;
#pragma unroll
        for (int kk = 0; kk < 4; ++kk) {
          int arow = f * 32 + l31;
          bf16x8 a = *(const bf16x8*)((const char*)Klds + arow * 128 +
                                      ((kk * 32 + gl * 16) ^ ((arow & 7) << 4)));
          sf[f] = __builtin_amdgcn_mfma_f32_32x32x16_bf16(a, bq[kk], sf[f], 0, 0, 0);
        }
      }
    }

    float mmax = -INFINITY;
#pragma unroll
    for (int f = 0; f < 8; ++f) {
      if (f < qt) {
#pragma unroll
        for (int r = 0; r < 16; ++r) mmax = fmaxf(mmax, sf[f][r]);
      } else if (f == qt) {
#pragma unroll
        for (int r = 0; r < 16; ++r) {
          int sloc = (r & 3) + 8 * (r >> 2) + 4 * gl;
          float v = (sloc <= l31) ? sf[f][r] : -INFINITY;
          mmax = fmaxf(mmax, v);
        }
      }
    }
    mmax = fmaxf(mmax, __shfl_xor(mmax, 32));

    float lsum = 0.0f;
#pragma unroll
    for (int f = 0; f < 8; ++f) {
      if (f <= qt) {
#pragma unroll
        for (int r = 0; r < 16; ++r) {
          float e = exp2f((sf[f][r] - mmax) * cexp);
          if (f == qt) {
            int sloc = (r & 3) + 8 * (r >> 2) + 4 * gl;
            e = (sloc <= l31) ? e : 0.0f;
          }
          sf[f][r] = e;
          lsum += e;
        }
      }
    }
    lsum += __shfl_xor(lsum, 32);

    f32x16 ao0 = {}, ao1 = {};
#pragma unroll
    for (int f = 0; f < 8; ++f) {
      if (f <= qt) {
        u32 a0 = pkbf(sf[f][0], sf[f][1]);
        u32 a1 = pkbf(sf[f][2], sf[f][3]);
        u32 b0 = pkbf(sf[f][4], sf[f][5]);
        u32 b1 = pkbf(sf[f][6], sf[f][7]);
        pl32swap(a0, b0);
        pl32swap(a1, b1);
        u32x4 te = {a0, a1, b0, b1};
        bf16x8 bpe = __builtin_bit_cast(bf16x8, te);
        u32 c0 = pkbf(sf[f][8], sf[f][9]);
        u32 c1 = pkbf(sf[f][10], sf[f][11]);
        u32 d0 = pkbf(sf[f][12], sf[f][13]);
        u32 d1 = pkbf(sf[f][14], sf[f][15]);
        pl32swap(c0, d0);
        pl32swap(c1, d1);
        u32x4 to = {c0, c1, d0, d1};
        bf16x8 bpo = __builtin_bit_cast(bf16x8, to);

        int se = (f * 32 + gl * 8) * 2;
        int so = se + 32;
        bf16x8 av0e = *(const bf16x8*)((char*)VT + l31 * 512 + (se ^ ((l31 & 7) << 4)));
        bf16x8 av1e = *(const bf16x8*)((char*)VT + (32 + l31) * 512 + (se ^ ((l31 & 7) << 4)));
        ao0 = __builtin_amdgcn_mfma_f32_32x32x16_bf16(av0e, bpe, ao0, 0, 0, 0);
        ao1 = __builtin_amdgcn_mfma_f32_32x32x16_bf16(av1e, bpe, ao1, 0, 0, 0);
        bf16x8 av0o = *(const bf16x8*)((char*)VT + l31 * 512 + (so ^ ((l31 & 7) << 4)));
        bf16x8 av1o = *(const bf16x8*)((char*)VT + (32 + l31) * 512 + (so ^ ((l31 & 7) << 4)));
        ao0 = __builtin_amdgcn_mfma_f32_32x32x16_bf16(av0o, bpo, ao0, 0, 0, 0);
        ao1 = __builtin_amdgcn_mfma_f32_32x32x16_bf16(av1o, bpo, ao1, 0, 0, 0);
      }
    }

    float rl = 1.0f / lsum;
    float* ob = out + ((size_t)b * NT + t0 + l31) * NH;
#pragma unroll
    for (int g = 0; g < 4; ++g) {
      float4 v0 = make_float4(ao0[4 * g + 0] * rl, ao0[4 * g + 1] * rl,
                              ao0[4 * g + 2] * rl, ao0[4 * g + 3] * rl);
      float4 v1 = make_float4(ao1[4 * g + 0] * rl, ao1[4 * g + 1] * rl,
                              ao1[4 * g + 2] * rl, ao1[4 * g + 3] * rl);
      *(float4*)(ob + 8 * g + 4 * gl) = v0;
      *(float4*)(ob + 32 + 8 * g + 4 * gl) = v1;
    }
  }
}

// ---------------- launch -----------------------------------------------------
extern "C" void kernel_launch(void* const* d_in, const int* in_sizes, int n_in,
                              void* d_out, int out_size, void* d_ws, size_t ws_size,
                              hipStream_t stream) {
  const float* x = (const float*)d_in[0];
  const float* wk = (const float*)d_in[1];
  const float* wq = (const float*)d_in[2];
  const float* wv = (const float*)d_in[3];
  float* out = (float*)d_out;

  char* ws = (char*)d_ws;
  u16* wb = (u16*)ws;                                   // 147456 B
  u16* kws = (u16*)(ws + (1 << 20));                    // 16 MB each
  u16* qws = kws + (size_t)NB * NT * NH;
  u16* vws = qws + (size_t)NB * NT * NH;

  wconv_k<<<288, 256, 0, stream>>>(wk, wq, wv, wb);
  qkv_gemm<<<512, 1024, 0, stream>>>(x, wb, kws, qws, vws);
  attn_k<<<512, 256, 0, stream>>>(kws, qws, vws, out);
}